// Round 1
// baseline (188.466 us; speedup 1.0000x reference)
//
#include <hip/hip_runtime.h>

// Problem constants (match reference)
#define NVIEW 11
#define RAD 5
#define GH 64
#define GW 64
#define WINSZ (NVIEW * NVIEW)   // 121
#define NCH 6
#define NOUT (NCH * WINSZ)      // 726
#define EPB 4                   // envs per block (1 wave each)
#define BLOCK 256

typedef __attribute__((ext_vector_type(4))) float f32x4;

// Phase 1: one wave per env gathers the 11x11 window into LDS (wave-synchronous,
// conflict-free lane==address writes). Phase 2: the whole block cooperatively
// writes its 4 envs' outputs (4*726 floats = 11616 B, contiguous and 16-B
// aligned since 4*NOUT*4 % 16 == 0) as 3 rounds of aligned nontemporal
// dwordx4 stores -- 12 wave-store insts/block vs 48 misaligned dword stores.
__global__ __launch_bounds__(BLOCK) void env_step_obs_kernel(
    const float* __restrict__ grids,          // (N, 64, 64)
    const float* __restrict__ agent_energy,   // (N,)
    const float* __restrict__ lut,            // (5,)
    const int*   __restrict__ agent_x,        // (N,)
    const int*   __restrict__ agent_y,        // (N,)
    const int*   __restrict__ actions,        // (N,)
    const int*   __restrict__ action_deltas,  // (9, 2) = (dy, dx)
    float*       __restrict__ out,            // (N, 6, 11, 11)
    int n_envs)
{
    __shared__ float win[EPB][WINSZ + 7];     // pad row to 128 floats
    __shared__ float ene[EPB];

    const int tid  = threadIdx.x;
    const int lane = tid & 63;
    const int wave = tid >> 6;
    const int n0   = blockIdx.x * EPB;
    const int n    = n0 + wave;               // env id (wave-uniform)

    if (n < n_envs) {
        // ---- per-env step logic (redundant per lane; same-address loads broadcast) ----
        const int a  = actions[n];
        const int dy = action_deltas[2 * a];
        const int dx = action_deltas[2 * a + 1];
        const int y0 = agent_y[n];
        const int x0 = agent_x[n];

        int ny = min(max(y0 + dy, 0), GH - 1);
        int nx = min(max(x0 + dx, 0), GW - 1);

        const float* g = grids + (size_t)n * (GH * GW);

        const float tgt = g[ny * GW + nx];
        if (tgt == 1.0f) { ny = y0; nx = x0; }          // blocked by wall: stay

        const float cell      = g[ny * GW + nx];
        const bool  is_food   = (cell == 2.0f);
        const bool  is_poison = (cell == 3.0f);
        const bool  consumed  = is_food || is_poison;
        const float reward    = (is_food ? 10.0f : 0.0f) - (is_poison ? 10.0f : 0.0f);
        if (lane == 0) ene[wave] = agent_energy[n] - 1.0f + reward;

        // ---- gather: lane stages window cells p = lane and p = lane + 64 ----
        #pragma unroll
        for (int r = 0; r < 2; ++r) {
            const int p = lane + r * 64;
            if (p < WINSZ) {
                const int i  = p / NVIEW;               // const divisor -> magic mul
                const int j  = p - i * NVIEW;
                const int yy = ny - RAD + i;
                const int xx = nx - RAD + j;
                float val = 1.0f;                       // WALL pad default
                if (yy >= 0 && yy < GH && xx >= 0 && xx < GW) val = g[yy * GW + xx];
                // consumed food/poison at landing cell == window center (5,5)
                if (consumed && p == (RAD * NVIEW + RAD)) val = 0.0f;
                win[wave][p] = val;
            }
        }
    }
    __syncthreads();

    // grid values are exact small integers {0,1,2,3}; lut[4] is unreachable
    const float l0 = lut[0], l1 = lut[1], l2 = lut[2], l3 = lut[3];

    // ---- cooperative aligned vectorized write of the block's 4 envs ----
    const int valid = min(n_envs - n0, EPB);
    const int lim   = valid * NOUT;                     // floats valid in this block
    float* base = out + (size_t)n0 * NOUT;              // 16-B aligned (n0*2904 % 16 == 0)

    #pragma unroll
    for (int round = 0; round < 3; ++round) {
        const int f = round * (BLOCK * 4) + tid * 4;    // flat float index, 16-B aligned
        if (f + 4 <= lim) {
            f32x4 o;
            #pragma unroll
            for (int k = 0; k < 4; ++k) {
                const int ff  = f + k;
                const int e   = ff / NOUT;              // const divisors -> magic mul
                const int rem = ff - e * NOUT;
                const int c   = rem / WINSZ;
                const int p   = rem - c * WINSZ;
                const float val = win[e][p];
                float ov;
                if      (c == 0) ov = (val == 2.0f) ? 1.0f : 0.0f;   // food mask
                else if (c == 1) ov = (val == 3.0f) ? 1.0f : 0.0f;   // poison mask
                else if (c == 2) ov = (val == 1.0f) ? 1.0f : 0.0f;   // wall mask
                else if (c == 3) ov = (val == 0.0f) ? l0
                                    : (val == 1.0f) ? l1
                                    : (val == 2.0f) ? l2 : l3;       // interestingness
                else if (c == 4) ov = val;                           // raw window
                else             ov = ene[e];                        // energy broadcast
                o[k] = ov;
            }
            __builtin_nontemporal_store(o, reinterpret_cast<f32x4*>(base + f));
        }
    }

    // scalar tail (only reachable when n_envs % EPB != 0: lim % 4 == 2)
    const int tail0 = lim & ~3;
    if (tid < lim - tail0) {
        const int ff  = tail0 + tid;
        const int e   = ff / NOUT;
        const int rem = ff - e * NOUT;
        const int c   = rem / WINSZ;
        const int p   = rem - c * WINSZ;
        const float val = win[e][p];
        float ov;
        if      (c == 0) ov = (val == 2.0f) ? 1.0f : 0.0f;
        else if (c == 1) ov = (val == 3.0f) ? 1.0f : 0.0f;
        else if (c == 2) ov = (val == 1.0f) ? 1.0f : 0.0f;
        else if (c == 3) ov = (val == 0.0f) ? l0
                            : (val == 1.0f) ? l1
                            : (val == 2.0f) ? l2 : l3;
        else if (c == 4) ov = val;
        else             ov = ene[e];
        base[ff] = ov;
    }
}

extern "C" void kernel_launch(void* const* d_in, const int* in_sizes, int n_in,
                              void* d_out, int out_size, void* d_ws, size_t ws_size,
                              hipStream_t stream) {
    const float* grids   = (const float*)d_in[0];
    const float* energy  = (const float*)d_in[1];
    const float* lut     = (const float*)d_in[2];
    const int*   agent_x = (const int*)d_in[3];
    const int*   agent_y = (const int*)d_in[4];
    // d_in[5] = agent_steps (unused by reference output)
    const int*   actions = (const int*)d_in[6];
    const int*   deltas  = (const int*)d_in[7];
    float*       out     = (float*)d_out;

    const int n_envs = in_sizes[1];                 // agent_energy count = N_ENVS
    const int blocks = (n_envs + EPB - 1) / EPB;

    env_step_obs_kernel<<<blocks, BLOCK, 0, stream>>>(
        grids, energy, lut, agent_x, agent_y, actions, deltas, out, n_envs);
}